// Round 6
// baseline (174.874 us; speedup 1.0000x reference)
//
#include <hip/hip_runtime.h>
#include <hip/hip_bf16.h>
#include <hip/hip_cooperative_groups.h>

namespace cg = cooperative_groups;

// Problem constants (fixed by reference). ALL float tensors are float32;
// indices int32. MFMA runs on bf16-converted fragments; accumulate + epilogue
// in fp32.
#define NB     131072   // batch
#define NCH    16       // charts
#define NPAIR  256      // (src,tgt) pair buckets
#define LDW    136      // LDS weight-row stride in bf16 elems (16B-aligned rows)
#define LDH    136      // LDS h-row stride in bf16 elems
#define CAP    1024     // sorted-slice chunk capacity (bucket avg 512, max ~640)

// Workspace layout (ints):
//   hist @0 (256) | bcur @256 (256) | off @512 (257) | sorted @769 (NB)
#define WS_HIST   0
#define WS_BCUR   256
#define WS_OFF    512
#define WS_SORTED 769
#define WS_BYTES  ((WS_SORTED + NB) * 4)   // 527,364

typedef short short8 __attribute__((ext_vector_type(8)));   // 8 x bf16 (4 VGPRs) MFMA frag
typedef float f32x4  __attribute__((ext_vector_type(4)));   // MFMA accumulator / fp32 vec

__device__ __forceinline__ short bfbits(float x) {
    union { __hip_bfloat16 h; short s; } u;
    u.h = __float2bfloat16(x);
    return u.s;
}

// Load 8 consecutive fp32 (32B, 16B-aligned) and convert to a bf16x8 MFMA frag.
__device__ __forceinline__ short8 cvt_frag(const float* __restrict__ p) {
    const f32x4 lo = *(const f32x4*)p;
    const f32x4 hi = *(const f32x4*)(p + 4);
    short8 r;
    r[0] = bfbits(lo[0]); r[1] = bfbits(lo[1]); r[2] = bfbits(lo[2]); r[3] = bfbits(lo[3]);
    r[4] = bfbits(hi[0]); r[5] = bfbits(hi[1]); r[6] = bfbits(hi[2]); r[7] = bfbits(hi[3]);
    return r;
}

// Pack two f32x4 into one bf16x8 MFMA frag.
__device__ __forceinline__ short8 pack_frag(f32x4 lo, f32x4 hi) {
    short8 r;
    r[0] = bfbits(lo[0]); r[1] = bfbits(lo[1]); r[2] = bfbits(lo[2]); r[3] = bfbits(lo[3]);
    r[4] = bfbits(hi[0]); r[5] = bfbits(hi[1]); r[6] = bfbits(hi[2]); r[7] = bfbits(hi[3]);
    return r;
}

// ---------------------------------------------------------------- k_sort ----
// ALL preprocessing in ONE cooperative launch (replaces init/hist/scan/scatter
// = 4 dispatches + 3 inter-launch gaps). hist and bcur are zeroed by a memset
// before launch. Phase structure proven in round-1's fused kernel:
//   1) per-block LDS histogram; keys+ranks stay in registers; block totals
//      atomicAdd'ed into global hist.
//   2) grid.sync -> every block redundantly scans hist in LDS. Block 0 writes
//      off[]. Per-block scatter base = global_excl_prefix + atomicAdd(bcur)
//      (bcur pre-zeroed => NO second grid.sync needed).
//   3) scatter from registers.
__global__ __launch_bounds__(256)
void k_sort(const int* __restrict__ si, const int* __restrict__ ti,
            int* __restrict__ hist, int* __restrict__ bcur,
            int* __restrict__ off, int* __restrict__ sorted) {
    __shared__ int sh[NPAIR];      // block-local bin counts
    __shared__ int sc[NPAIR];      // scan workspace
    __shared__ int sbase[NPAIR];   // scatter base per bin
    cg::grid_group grid = cg::this_grid();
    const int t = threadIdx.x, bid = blockIdx.x;

    sh[t] = 0;
    __syncthreads();
    int key[4], rank[4];
    const int base = bid * 1024 + t;
#pragma unroll
    for (int j = 0; j < 4; ++j) {
        const int i = base + j * 256;                       // coalesced
        const int k = (si[i] * NCH + ti[i]) & (NPAIR - 1);  // masked: never OOB
        key[j]  = k;
        rank[j] = atomicAdd(&sh[k], 1);
    }
    __syncthreads();
    const int cnt = sh[t];
    if (cnt) atomicAdd(&hist[t], cnt);                      // device-scope
    grid.sync();

    // redundant per-block scan of the global histogram
    const int v = __hip_atomic_load(&hist[t], __ATOMIC_RELAXED, __HIP_MEMORY_SCOPE_AGENT);
    sc[t] = v;
    __syncthreads();
#pragma unroll
    for (int d = 1; d < NPAIR; d <<= 1) {
        const int x = (t >= d) ? sc[t - d] : 0;
        __syncthreads();
        sc[t] += x;
        __syncthreads();
    }
    if (bid == 0) {
        off[t + 1] = sc[t];        // inclusive -> off[1..256]
        if (t == 0) off[0] = 0;
    }
    const int excl = sc[t] - v;    // global exclusive prefix for bin t
    sbase[t] = cnt ? (excl + atomicAdd(&bcur[t], cnt)) : 0;
    __syncthreads();
#pragma unroll
    for (int j = 0; j < 4; ++j) {
        const int slot = sbase[key[j]] + rank[j];
        if (slot >= 0 && slot < NB)
            sorted[slot] = base + j * 256;
    }
}

// ---------------------------------------------------------------- k_gemm ----
// ROUND-4 KERNEL, VERBATIM (best measured: 145.4us total). One block per
// bucket, 512 threads = 8 waves, wave-autonomous zero-barrier main loop,
// 32-row groups: two 16-row halves share every B fragment ds_read (8 reads
// feed 16 MFMAs per k-step), dual accumulator chains for ILP, 1-group-ahead
// register prefetch of the z gather. Round-5's 16-row/DMA variant regressed
// 37->61us (halved MFMA per iteration exposed the latency chain) — do not
// shrink the group size.
__global__ __launch_bounds__(512, 2)
void k_gemm(const float* __restrict__ z,
            const float* __restrict__ encw,
            const float* __restrict__ decw,
            const float* __restrict__ cpar,
            const float* __restrict__ dpar,
            const int* __restrict__ off,
            const int* __restrict__ sorted,
            float* __restrict__ out) {
    __shared__ int sRowLds[CAP];
    __shared__ __align__(16) __hip_bfloat16 sW1[128 * LDW];
    __shared__ __align__(16) __hip_bfloat16 sW2[128 * LDW];
    __shared__ __align__(16) __hip_bfloat16 sH[8 * 32 * LDH];

    const int bucket = blockIdx.x;
    const int srcc = bucket >> 4;
    const int tgtc = bucket & (NCH - 1);
    const int beg = off[bucket];
    const int end = off[bucket + 1];

    const int tid  = threadIdx.x;
    const int lane = tid & 63;
    const int wv   = tid >> 6;
    const int lr   = lane & 15;
    const int lhi  = lane >> 4;

    {
        const float* W1 = encw + srcc * 16384;
        const float* W2 = decw + tgtc * 16384;
#pragma unroll
        for (int it = 0; it < 4; ++it) {
            const int f = (it * 512 + tid) * 8;
            const int row = f >> 7, col = f & 127;
            *(short8*)(sW1 + row * LDW + col) = cvt_frag(W1 + f);
            *(short8*)(sW2 + row * LDW + col) = cvt_frag(W2 + f);
        }
    }

    float cb[8], db[8];
#pragma unroll
    for (int nt = 0; nt < 8; ++nt) {
        cb[nt] = cpar[srcc * 128 + nt * 16 + lr];
        db[nt] = dpar[tgtc * 128 + nt * 16 + lr];
    }

    __hip_bfloat16* const hs = sH + wv * (32 * LDH);
    f32x4 bufA[8], bufB[8];

    auto pf = [&](int g) {
        const int r0 = sRowLds[(g << 5) + lr];
        const int r1 = sRowLds[(g << 5) + 16 + lr];
        const float* p0 = z + (long)(r0 < 0 ? 0 : r0) * 128 + lhi * 8;
        const float* p1 = z + (long)(r1 < 0 ? 0 : r1) * 128 + lhi * 8;
#pragma unroll
        for (int k = 0; k < 4; ++k) {
            bufA[2 * k]     = *(const f32x4*)(p0 + k * 32);
            bufA[2 * k + 1] = *(const f32x4*)(p0 + k * 32 + 4);
            bufB[2 * k]     = *(const f32x4*)(p1 + k * 32);
            bufB[2 * k + 1] = *(const f32x4*)(p1 + k * 32 + 4);
        }
    };

    for (int cb0 = beg; cb0 < end; cb0 += CAP) {
        const int cnt = min(end - cb0, CAP);
        __syncthreads();
        for (int i = tid; i < CAP; i += 512) {
            int v = (i < cnt) ? sorted[cb0 + i] : -1;
            sRowLds[i] = ((unsigned)v < (unsigned)NB) ? v : -1;
        }
        __syncthreads();

        const int ng = (cnt + 31) >> 5;
        int g = wv;
        if (g < ng) pf(g);
        while (g < ng) {
            short8 a0[4], a1[4];
#pragma unroll
            for (int k = 0; k < 4; ++k) {
                a0[k] = pack_frag(bufA[2 * k], bufA[2 * k + 1]);
                a1[k] = pack_frag(bufB[2 * k], bufB[2 * k + 1]);
            }
            const int gn = g + 8;
            if (gn < ng) pf(gn);

            f32x4 acc0[8], acc1[8];
#pragma unroll
            for (int nt = 0; nt < 8; ++nt) { acc0[nt] = (f32x4)(0.0f); acc1[nt] = (f32x4)(0.0f); }

#pragma unroll
            for (int k = 0; k < 4; ++k) {
#pragma unroll
                for (int nt = 0; nt < 8; ++nt) {
                    const short8 b = *(const short8*)(sW1 + (nt * 16 + lr) * LDW + k * 32 + lhi * 8);
                    acc0[nt] = __builtin_amdgcn_mfma_f32_16x16x32_bf16(a0[k], b, acc0[nt], 0, 0, 0);
                    acc1[nt] = __builtin_amdgcn_mfma_f32_16x16x32_bf16(a1[k], b, acc1[nt], 0, 0, 0);
                }
            }

#pragma unroll
            for (int nt = 0; nt < 8; ++nt)
#pragma unroll
                for (int r = 0; r < 4; ++r) {
                    hs[(lhi * 4 + r) * LDH + nt * 16 + lr]      = __float2bfloat16(acc0[nt][r] + cb[nt]);
                    hs[(16 + lhi * 4 + r) * LDH + nt * 16 + lr] = __float2bfloat16(acc1[nt][r] + cb[nt]);
                }

#pragma unroll
            for (int nt = 0; nt < 8; ++nt) { acc0[nt] = (f32x4)(0.0f); acc1[nt] = (f32x4)(0.0f); }

#pragma unroll
            for (int k = 0; k < 4; ++k) {
                const short8 ah0 = *(const short8*)(hs + lr * LDH + k * 32 + lhi * 8);
                const short8 ah1 = *(const short8*)(hs + (16 + lr) * LDH + k * 32 + lhi * 8);
#pragma unroll
                for (int nt = 0; nt < 8; ++nt) {
                    const short8 b = *(const short8*)(sW2 + (nt * 16 + lr) * LDW + k * 32 + lhi * 8);
                    acc0[nt] = __builtin_amdgcn_mfma_f32_16x16x32_bf16(ah0, b, acc0[nt], 0, 0, 0);
                    acc1[nt] = __builtin_amdgcn_mfma_f32_16x16x32_bf16(ah1, b, acc1[nt], 0, 0, 0);
                }
            }

            {
                int g0[4], g1[4];
#pragma unroll
                for (int r = 0; r < 4; ++r) {
                    g0[r] = sRowLds[(g << 5) + lhi * 4 + r];
                    g1[r] = sRowLds[(g << 5) + 16 + lhi * 4 + r];
                }
#pragma unroll
                for (int nt = 0; nt < 8; ++nt)
#pragma unroll
                    for (int r = 0; r < 4; ++r) {
                        if (g0[r] >= 0)
                            out[(long)g0[r] * 128 + nt * 16 + lr] = acc0[nt][r] + db[nt];
                        if (g1[r] >= 0)
                            out[(long)g1[r] * 128 + nt * 16 + lr] = acc1[nt][r] + db[nt];
                    }
            }
            g = gn;
        }
    }
}

// =========================================================================
// Non-cooperative preprocessing fallback (round-4 path, proven): used only
// if cooperative launch is unavailable or fails.
// =========================================================================
__global__ void k_init(int* __restrict__ hist) {
    hist[threadIdx.x] = 0;
}

__global__ __launch_bounds__(256) void k_hist(const int* __restrict__ si,
                                              const int* __restrict__ ti,
                                              int* __restrict__ hist) {
    __shared__ int sh[NPAIR];
    const int t = threadIdx.x;
    sh[t] = 0;
    __syncthreads();
    const int base = blockIdx.x * 1024 + t;
#pragma unroll
    for (int j = 0; j < 4; ++j) {
        const int i = base + j * 256;
        const int k = (si[i] * NCH + ti[i]) & (NPAIR - 1);
        atomicAdd(&sh[k], 1);
    }
    __syncthreads();
    if (sh[t]) atomicAdd(&hist[t], sh[t]);
}

__global__ __launch_bounds__(256) void k_scan(int* __restrict__ hist,
                                              int* __restrict__ off) {
    __shared__ int s[NPAIR];
    const int t = threadIdx.x;
    const int v = hist[t];
    s[t] = v;
    __syncthreads();
#pragma unroll
    for (int d = 1; d < NPAIR; d <<= 1) {
        const int x = (t >= d) ? s[t - d] : 0;
        __syncthreads();
        s[t] += x;
        __syncthreads();
    }
    off[t + 1] = s[t];
    if (t == 0) off[0] = 0;
    hist[t] = s[t] - v;                // exclusive prefix -> cursor start
}

__global__ __launch_bounds__(256) void k_scatter(const int* __restrict__ si,
                                                 const int* __restrict__ ti,
                                                 int* __restrict__ cursor,
                                                 int* __restrict__ sorted) {
    __shared__ int sh[NPAIR];
    __shared__ int sbase[NPAIR];
    const int t = threadIdx.x;
    sh[t] = 0;
    __syncthreads();
    int key[4], rank[4];
    const int base = blockIdx.x * 1024 + t;
#pragma unroll
    for (int j = 0; j < 4; ++j) {
        const int i = base + j * 256;
        const int k = (si[i] * NCH + ti[i]) & (NPAIR - 1);
        key[j]  = k;
        rank[j] = atomicAdd(&sh[k], 1);
    }
    __syncthreads();
    sbase[t] = sh[t] ? atomicAdd(&cursor[t], sh[t]) : 0;
    __syncthreads();
#pragma unroll
    for (int j = 0; j < 4; ++j) {
        const int slot = sbase[key[j]] + rank[j];
        if (slot >= 0 && slot < NB)
            sorted[slot] = base + j * 256;
    }
}

// ------------------------------------------------------------- k_fallback ---
// Zero-workspace correct path: one wave per row, fp32 VALU dot products.
__global__ __launch_bounds__(256)
void k_fallback(const float* __restrict__ z,
                const int* __restrict__ si, const int* __restrict__ ti,
                const float* __restrict__ ew,
                const float* __restrict__ dw,
                const float* __restrict__ cp,
                const float* __restrict__ dp,
                float* __restrict__ out) {
    __shared__ float sh[4][128];
    const int lane = threadIdx.x & 63, wv = threadIdx.x >> 6;
    for (int row = blockIdx.x * 4 + wv; row < NB; row += (int)gridDim.x * 4) {
        const int sc = si[row] & (NCH - 1), tc = ti[row] & (NCH - 1);
        const float* zr = z + (long)row * 128;
        const float* W1 = ew + sc * 16384;
        float h0 = cp[sc * 128 + lane];
        float h1 = cp[sc * 128 + lane + 64];
        for (int d = 0; d < 128; ++d) {
            const float zv = zr[d];
            h0 += zv * W1[lane * 128 + d];
            h1 += zv * W1[(lane + 64) * 128 + d];
        }
        sh[wv][lane] = h0;
        sh[wv][lane + 64] = h1;
        __syncthreads();
        const float* W2 = dw + tc * 16384;
        float o0 = dp[tc * 128 + lane];
        float o1 = dp[tc * 128 + lane + 64];
        for (int r = 0; r < 128; ++r) {
            const float hv = sh[wv][r];
            o0 += hv * W2[lane * 128 + r];
            o1 += hv * W2[(lane + 64) * 128 + r];
        }
        out[(long)row * 128 + lane] = o0;
        out[(long)row * 128 + lane + 64] = o1;
        __syncthreads();
    }
}

// ----------------------------------------------------------------- launch ---
extern "C" void kernel_launch(void* const* d_in, const int* in_sizes, int n_in,
                              void* d_out, int out_size, void* d_ws, size_t ws_size,
                              hipStream_t stream) {
    // Reference dtypes: all float tensors float32, indices int32, output float32.
    const float* z  = (const float*)d_in[0];
    const int*   si = (const int*)d_in[1];
    const int*   ti = (const int*)d_in[2];
    const float* ew = (const float*)d_in[3];
    const float* dw = (const float*)d_in[4];
    const float* cp = (const float*)d_in[5];
    const float* dp = (const float*)d_in[6];
    float* out = (float*)d_out;

    if (ws_size >= (size_t)WS_BYTES) {
        int* hist   = (int*)d_ws + WS_HIST;    // 256 (also cursor in fallback path)
        int* bcur   = (int*)d_ws + WS_BCUR;    // 256
        int* off    = (int*)d_ws + WS_OFF;     // 257
        int* sorted = (int*)d_ws + WS_SORTED;  // NB

        static int coopChecked = 0, coopOK = 0;
        if (!coopChecked) {
            coopChecked = 1;
            int dev = 0;
            (void)hipGetDevice(&dev);
            (void)hipDeviceGetAttribute(&coopOK, hipDeviceAttributeCooperativeLaunch, dev);
        }

        bool sorted_ok = false;
        if (coopOK) {
            (void)hipMemsetAsync(hist, 0, 2 * NPAIR * sizeof(int), stream);  // hist + bcur
            void* args[] = { (void*)&si, (void*)&ti, (void*)&hist,
                             (void*)&bcur, (void*)&off, (void*)&sorted };
            hipError_t e = hipLaunchCooperativeKernel((const void*)k_sort,
                                                      dim3(128), dim3(256),
                                                      args, 0, stream);
            if (e == hipSuccess) sorted_ok = true;
            else (void)hipGetLastError();      // clear; fall through to legacy path
        }
        if (!sorted_ok) {
            k_init<<<1, NPAIR, 0, stream>>>(hist);
            k_hist<<<128, 256, 0, stream>>>(si, ti, hist);
            k_scan<<<1, NPAIR, 0, stream>>>(hist, off);
            k_scatter<<<128, 256, 0, stream>>>(si, ti, hist, sorted);
        }
        k_gemm<<<NPAIR, 512, 0, stream>>>(z, ew, dw, cp, dp, off, sorted, out);
    } else {
        k_fallback<<<1024, 256, 0, stream>>>(z, si, ti, ew, dw, cp, dp, out);
    }
}